// Round 7
// baseline (621.046 us; speedup 1.0000x reference)
//
#include <hip/hip_runtime.h>
#include <math.h>

// Problem constants (MicroGPT)
constexpr int Bc  = 16;
constexpr int Tc  = 2048;
constexpr int Cc  = 16;
constexpr int Hc  = 2;
constexpr int HSc = 8;
constexpr int Lc  = 2;
constexpr int Vc  = 256;
constexpr int BT  = Bc * Tc;          // 32768 tokens
constexpr float EPSc = 1e-5f;

// Attention tiling: K-chunk split + 4 queries/thread
constexpr int KC  = 128;              // keys per chunk (LDS tile)
constexpr int NCH = Tc / KC;          // 16 chunks
constexpr int QB  = 1024;             // queries per block (256 thr x 4 ILP)
constexpr int NQB = Tc / QB;          // 2 query blocks per (b,h)

constexpr int NBLK = 512;             // grid size (2 blocks/CU, co-resident)

typedef float f2 __attribute__((ext_vector_type(2)));

__device__ inline float shx(float v, int m) { return __shfl_xor(v, m, 64); }

#define AGENT __HIP_MEMORY_SCOPE_AGENT

// ---------------------------------------------------------------------------
// Manual grid barrier.  bar[0]=count, bar[1]=generation, bar[2]=init flag.
// Safe because all NBLK blocks are co-resident (see launch_bounds note).
// Guarded spins: a broken co-residency assumption fails loudly, not a hang.
// ---------------------------------------------------------------------------
__device__ inline void gridbar(unsigned* bar) {
  __syncthreads();
  if (threadIdx.x == 0) {
    __threadfence();   // publish this block's writes (device scope)
    unsigned gen = __hip_atomic_load(bar + 1, __ATOMIC_RELAXED, AGENT);
    unsigned arrived = __hip_atomic_fetch_add(bar, 1u, __ATOMIC_ACQ_REL, AGENT);
    if (arrived == (unsigned)(NBLK - 1)) {
      __hip_atomic_store(bar, 0u, __ATOMIC_RELAXED, AGENT);
      __hip_atomic_fetch_add(bar + 1, 1u, __ATOMIC_RELEASE, AGENT);
    } else {
      long guard = 0;
      while (__hip_atomic_load(bar + 1, __ATOMIC_ACQUIRE, AGENT) == gen &&
             guard < (1L << 31)) {
        guard++;
        __builtin_amdgcn_s_sleep(2);
      }
    }
  }
  __syncthreads();
}

// ---------------------------------------------------------------------------
// LN helper
// ---------------------------------------------------------------------------
__device__ inline void layernorm16(const float* xr, float* h,
                                   const float* g, const float* b) {
  float m = 0.f;
#pragma unroll
  for (int c = 0; c < Cc; c++) m += xr[c];
  m *= (1.f / Cc);
  float var = 0.f;
#pragma unroll
  for (int c = 0; c < Cc; c++) { float d = xr[c] - m; var += d * d; }
  var *= (1.f / Cc);
  float rs = rsqrtf(var + EPSc);
#pragma unroll
  for (int c = 0; c < Cc; c++) h[c] = (xr[c] - m) * rs * g[c] + b[c];
}

// ---------------------------------------------------------------------------
// 4-lane-coop QKV: lane j computes s={2j,2j+1} of every (head, q/k/v) vector
// ---------------------------------------------------------------------------
__device__ inline void qkv_store_lane(const float* h, const float* swq,
                                      const float* swk, const float* swv,
                                      int bb, int tt, int j,
                                      float* __restrict__ q,
                                      float* __restrict__ k,
                                      float* __restrict__ v) {
#pragma unroll
  for (int hh = 0; hh < Hc; hh++) {
    float q0 = 0.f, q1 = 0.f, k0 = 0.f, k1 = 0.f, v0 = 0.f, v1 = 0.f;
#pragma unroll
    for (int c = 0; c < Cc; c++) {
      float hv = h[c];
      const float* wqp = swq + (hh * Cc + c) * HSc + 2 * j;
      const float* wkp = swk + (hh * Cc + c) * HSc + 2 * j;
      const float* wvp = swv + (hh * Cc + c) * HSc + 2 * j;
      q0 += hv * wqp[0]; q1 += hv * wqp[1];
      k0 += hv * wkp[0]; k1 += hv * wkp[1];
      v0 += hv * wvp[0]; v1 += hv * wvp[1];
    }
    long base = ((long)(bb * Hc + hh) * Tc + tt) * HSc;
    ((float2*)(q + base))[j] = make_float2(q0, q1);
    ((float2*)(k + base))[j] = make_float2(k0, k1);
    ((float2*)(v + base))[j] = make_float2(v0, v1);
  }
}

// ---------------------------------------------------------------------------
// 4-lane cooperative tail (identical to R5)
// ---------------------------------------------------------------------------
__device__ inline void coop_tail(
    const float* __restrict__ pacc, const float* __restrict__ pl,
    const float* swo, const float* sw1, const float* sw2,
    const float* sg2, const float* sb2, int bb, int tt, int j, float* xr) {
  // --- A: attention partial reduce
  int hh  = j & 1;
  int bh  = bb * Hc + hh;
  int nch = tt / KC + 1;
  float o8[8] = {0,0,0,0,0,0,0,0};
  float l = 0.f;
#pragma unroll 2
  for (int ch = (j >> 1); ch < nch; ch += 2) {
    long rec = (long)(bh * NCH + ch) * Tc + tt;
    const float4* pa = (const float4*)(pacc + rec * 8);
    float4 a = pa[0], b = pa[1];
    o8[0]+=a.x; o8[1]+=a.y; o8[2]+=a.z; o8[3]+=a.w;
    o8[4]+=b.x; o8[5]+=b.y; o8[6]+=b.z; o8[7]+=b.w;
    l += pl[rec];
  }
#pragma unroll
  for (int s = 0; s < 8; s++) o8[s] += shx(o8[s], 2);
  l += shx(l, 2);
  float inv = 1.f / l;
  float own[8], oth[8];
#pragma unroll
  for (int s = 0; s < 8; s++) own[s] = o8[s] * inv;
#pragma unroll
  for (int s = 0; s < 8; s++) oth[s] = shx(own[s], 1);
  float orow[Cc];
#pragma unroll
  for (int s = 0; s < 8; s++) {
    orow[s]     = (hh == 0) ? own[s] : oth[s];
    orow[8 + s] = (hh == 0) ? oth[s] : own[s];
  }
  // --- B: proj, c = 4j..4j+3
  float xc[4];
#pragma unroll
  for (int qq = 0; qq < 4; qq++) {
    int c = 4 * j + qq;
    float acc = xr[c];
#pragma unroll
    for (int kk = 0; kk < Cc; kk++) acc += orow[kk] * swo[c * 17 + kk];
    xc[qq] = acc;
  }
  {
    float p[4];
#pragma unroll
    for (int qq = 0; qq < 4; qq++) p[qq] = shx(xc[qq], 1);
    bool lo = (j & 1) == 0;
    float a8[8], b8[8];
#pragma unroll
    for (int qq = 0; qq < 4; qq++) {
      a8[qq]     = lo ? xc[qq] : p[qq];
      a8[4 + qq] = lo ? p[qq] : xc[qq];
    }
#pragma unroll
    for (int s = 0; s < 8; s++) b8[s] = shx(a8[s], 2);
    bool lo2 = (j & 2) == 0;
#pragma unroll
    for (int s = 0; s < 8; s++) {
      xr[s]     = lo2 ? a8[s] : b8[s];
      xr[8 + s] = lo2 ? b8[s] : a8[s];
    }
  }
  // --- C: MLP, hidden units j*16..j*16+15
  float h[Cc];
  layernorm16(xr, h, sg2, sb2);
  float r[Cc];
#pragma unroll
  for (int c = 0; c < Cc; c++) r[c] = 0.f;
#pragma unroll
  for (int i = 0; i < 16; i++) {
    int jj = j * 16 + i;
    float acc = 0.f;
#pragma unroll
    for (int c = 0; c < Cc; c++) acc += h[c] * sw1[jj * 17 + c];
    acc = fmaxf(acc, 0.f);
#pragma unroll
    for (int c = 0; c < Cc; c++) r[c] += acc * sw2[c * 64 + jj];
  }
#pragma unroll
  for (int c = 0; c < Cc; c++) r[c] += shx(r[c], 1);
#pragma unroll
  for (int c = 0; c < Cc; c++) r[c] += shx(r[c], 2);
#pragma unroll
  for (int c = 0; c < Cc; c++) xr[c] += r[c];
}

// ---------------------------------------------------------------------------
// Fused whole-model kernel with manual grid barrier.
// 512 blocks x 256 threads. launch_bounds(256,2) => VGPR<=256 => every CU
// hosts >=2 blocks (LDS 13.9KB, 8 waves) => all 512 blocks co-resident.
// ---------------------------------------------------------------------------
struct GPTParams {
  const int* idx;
  const float *tok, *pos, *wq, *wk, *wv, *wo;
  const float *ln1g, *ln1b, *ln2g, *ln2b, *w1, *w2, *lnfg, *lnfb;
  float *out, *x, *q, *k, *v, *pacc, *pl;
  unsigned* bar;
};

__global__ __launch_bounds__(256, 2) void microgpt_fused(GPTParams P) {
  __shared__ float smem[3472];
  int tid = threadIdx.x;
  int blk = blockIdx.x;            // 0..511

  // ---- barrier init gate (d_ws is 0xAA-poisoned before every launch) ----
  if (tid == 0) {
    if (blk == 0) {
      __hip_atomic_store(P.bar + 0, 0u, __ATOMIC_RELAXED, AGENT);
      __hip_atomic_store(P.bar + 1, 0u, __ATOMIC_RELAXED, AGENT);
      __hip_atomic_store(P.bar + 2, 0xC0FFEEu, __ATOMIC_RELEASE, AGENT);
    } else {
      long guard = 0;
      while (__hip_atomic_load(P.bar + 2, __ATOMIC_ACQUIRE, AGENT) !=
                 0xC0FFEEu && guard < (1L << 31)) {
        guard++;
        __builtin_amdgcn_s_sleep(2);
      }
    }
  }
  __syncthreads();

  int tk = blk * 64 + (tid >> 2);  // token for E/M/F phases
  int j  = tid & 3;
  int tt = tk & (Tc - 1);
  int bb = tk >> 11;

  // ===== Phase E: embed + LN1 + QKV (layer 0) =====
  {
    float* swq = smem;       float* swk = smem + 256;  float* swv = smem + 512;
    float* sg  = smem + 768; float* sb  = smem + 784;
    swq[tid] = P.wq[tid];
    swk[tid] = P.wk[tid];
    swv[tid] = P.wv[tid];
    if (tid < Cc) { sg[tid] = P.ln1g[tid]; sb[tid] = P.ln1b[tid]; }
    __syncthreads();
    int id = P.idx[tk];
    float xr[Cc];
    const float4* te = (const float4*)(P.tok + id * Cc);
    const float4* pe = (const float4*)(P.pos + tt * Cc);
#pragma unroll
    for (int i = 0; i < 4; i++) {
      float4 a = te[i], p = pe[i];
      xr[4*i] = a.x + p.x; xr[4*i+1] = a.y + p.y;
      xr[4*i+2] = a.z + p.z; xr[4*i+3] = a.w + p.w;
    }
    ((float4*)(P.x + (long)tk * Cc))[j] =
        make_float4(xr[4*j], xr[4*j+1], xr[4*j+2], xr[4*j+3]);
    float h[Cc];
    layernorm16(xr, h, sg, sb);
    qkv_store_lane(h, swq, swk, swv, bb, tt, j, P.q, P.k, P.v);
  }
  gridbar(P.bar);

  for (int l = 0; l < Lc; l++) {
    // ===== Phase A: causal flash attention (2 paired tasks per block) =====
    {
      float* sk = smem;
      float* sv = smem + KC * HSc;
      for (int rep = 0; rep < 2; rep++) {
        int task = rep ? (1023 - blk) : blk;   // pairs (qb0,ch) with (qb1,15-ch)
        int qb = task >> 9;
        int ch = (task >> 5) & 15;
        int bh = task & 31;
        int k0 = ch * KC;
        bool skip = (k0 >= (qb + 1) * QB);     // chunk fully in causal future
        __syncthreads();                        // protect smem from prior task
        if (!skip) {
          ((float4*)sk)[tid] =
              ((const float4*)(P.k + ((long)bh * Tc + k0) * HSc))[tid];
          ((float4*)sv)[tid] =
              ((const float4*)(P.v + ((long)bh * Tc + k0) * HSc))[tid];
        }
        __syncthreads();
        if (skip) continue;

        const float pre = 0.35355339059327373f * 1.4426950408889634f;
        int q0 = qb * QB + tid;
        f2 qr[4][4];
        f2 acc[4][4];
        float l4[4] = {0.f, 0.f, 0.f, 0.f};
        int kmax[4];
#pragma unroll
        for (int i = 0; i < 4; i++) {
          int qi = q0 + 256 * i;
          const f2* qp = (const f2*)(P.q + ((long)bh * Tc + qi) * HSc);
#pragma unroll
          for (int jj = 0; jj < 4; jj++) {
            qr[i][jj] = qp[jj] * pre;
            acc[i][jj] = {0.f, 0.f};
          }
          int km = qi + 1 - k0;
          kmax[i] = km < 0 ? 0 : (km > KC ? KC : km);
        }

        const f2* skp = (const f2*)sk;
        const f2* svp = (const f2*)sv;

#define ATTN_STEP(u, MASKED)                                              \
  {                                                                       \
    f2 k0v = skp[(u)*4+0], k1v = skp[(u)*4+1],                            \
       k2v = skp[(u)*4+2], k3v = skp[(u)*4+3];                            \
    f2 v0v = svp[(u)*4+0], v1v = svp[(u)*4+1],                            \
       v2v = svp[(u)*4+2], v3v = svp[(u)*4+3];                            \
    _Pragma("unroll")                                                     \
    for (int i = 0; i < 4; i++) {                                         \
      f2 d = qr[i][0] * k0v;                                              \
      d += qr[i][1] * k1v;                                                \
      d += qr[i][2] * k2v;                                                \
      d += qr[i][3] * k3v;                                                \
      float s = d.x + d.y;                                                \
      float p = __builtin_amdgcn_exp2f(s);                                \
      if (MASKED) p = ((u) < kmax[i]) ? p : 0.f;                          \
      l4[i] += p;                                                         \
      acc[i][0] += p * v0v;                                               \
      acc[i][1] += p * v1v;                                               \
      acc[i][2] += p * v2v;                                               \
      acc[i][3] += p * v3v;                                               \
    }                                                                     \
  }

        bool full = (k0 + KC) <= qb * QB;
        if (full) {
#pragma unroll 2
          for (int u = 0; u < KC; u++) ATTN_STEP(u, false)
        } else {
          int bound = kmax[3];
          for (int u = 0; u < bound; u++) ATTN_STEP(u, true)
        }
#undef ATTN_STEP

        long rec = (long)(bh * NCH + ch) * Tc;
#pragma unroll
        for (int i = 0; i < 4; i++) {
          if (kmax[i] > 0) {
            int qi = q0 + 256 * i;
            float4* pa = (float4*)(P.pacc + (rec + qi) * 8);
            pa[0] = make_float4(acc[i][0].x, acc[i][0].y,
                                acc[i][1].x, acc[i][1].y);
            pa[1] = make_float4(acc[i][2].x, acc[i][2].y,
                                acc[i][3].x, acc[i][3].y);
            P.pl[rec + qi] = l4[i];
          }
        }
      }
    }
    gridbar(P.bar);

    if (l == 0) {
      // ===== Phase M: layer-0 epilogue + layer-1 LN1+QKV =====
      float* swo = smem;           float* sw1 = smem + 272;
      float* sw2 = smem + 1360;    float* swq = smem + 2384;
      float* swk = smem + 2640;    float* swv = smem + 2896;
      float* sg2 = smem + 3152;    float* sb2 = smem + 3168;
      float* sg1 = smem + 3184;    float* sb1 = smem + 3200;
      const float* wq1 = P.wq + Hc * Cc * HSc;
      const float* wk1 = P.wk + Hc * Cc * HSc;
      const float* wv1 = P.wv + Hc * Cc * HSc;
      swq[tid] = wq1[tid]; swk[tid] = wk1[tid]; swv[tid] = wv1[tid];
      { int rr = tid >> 4, c = tid & 15; swo[rr * 17 + c] = P.wo[tid]; }
#pragma unroll
      for (int t = tid; t < 1024; t += 256) {
        int jj = t >> 4, c = t & 15;
        sw1[jj * 17 + c] = P.w1[t];
        sw2[t] = P.w2[t];
      }
      if (tid < Cc) {
        sg2[tid] = P.ln2g[tid]; sb2[tid] = P.ln2b[tid];
        sg1[tid] = P.ln1g[Cc + tid]; sb1[tid] = P.ln1b[Cc + tid];
      }
      __syncthreads();

      float xr[Cc];
      const float4* xp = (const float4*)(P.x + (long)tk * Cc);
#pragma unroll
      for (int i = 0; i < 4; i++) {
        float4 a = xp[i];
        xr[4*i]=a.x; xr[4*i+1]=a.y; xr[4*i+2]=a.z; xr[4*i+3]=a.w;
      }
      coop_tail(P.pacc, P.pl, swo, sw1, sw2, sg2, sb2, bb, tt, j, xr);
      ((float4*)(P.x + (long)tk * Cc))[j] =
          make_float4(xr[4*j], xr[4*j+1], xr[4*j+2], xr[4*j+3]);
      float h[Cc];
      layernorm16(xr, h, sg1, sb1);
      qkv_store_lane(h, swq, swk, swv, bb, tt, j, P.q, P.k, P.v);
      gridbar(P.bar);
    } else {
      // ===== Phase F: layer-1 epilogue + LNf + tied lm_head =====
      float* swo = smem;           float* sw1 = smem + 272;
      float* sw2 = smem + 1360;    float* sg2 = smem + 2384;
      float* sb2 = smem + 2400;    float* sgf = smem + 2416;
      float* sbf = smem + 2432;    float* sh  = smem + 2448;   // 64*16
      { int rr = tid >> 4, c = tid & 15; swo[rr * 17 + c] = P.wo[256 + tid]; }
#pragma unroll
      for (int t = tid; t < 1024; t += 256) {
        int jj = t >> 4, c = t & 15;
        sw1[jj * 17 + c] = P.w1[1024 + t];
        sw2[t] = P.w2[1024 + t];
      }
      if (tid < Cc) {
        sg2[tid] = P.ln2g[Cc + tid]; sb2[tid] = P.ln2b[Cc + tid];
        sgf[tid] = P.lnfg[tid];      sbf[tid] = P.lnfb[tid];
      }
      __syncthreads();

      float xr[Cc];
      const float4* xp = (const float4*)(P.x + (long)tk * Cc);
#pragma unroll
      for (int i = 0; i < 4; i++) {
        float4 a = xp[i];
        xr[4*i]=a.x; xr[4*i+1]=a.y; xr[4*i+2]=a.z; xr[4*i+3]=a.w;
      }
      coop_tail(P.pacc, P.pl, swo, sw1, sw2, sg2, sb2, bb, tt, j, xr);
      float h[Cc];
      layernorm16(xr, h, sgf, sbf);
      ((float4*)(sh + (tid >> 2) * Cc))[j] =
          make_float4(h[4*j], h[4*j+1], h[4*j+2], h[4*j+3]);
      __syncthreads();

      // head: thread = vocab id, 64 tokens from LDS (broadcast reads)
      float4 e0, e1, e2, e3;
      {
        const float4* ep = (const float4*)(P.tok + tid * Cc);
        e0 = ep[0]; e1 = ep[1]; e2 = ep[2]; e3 = ep[3];
      }
      int row0 = blk * 64;
#pragma unroll 4
      for (int t = 0; t < 64; t++) {
        const float4* hp = (const float4*)(sh + t * Cc);
        float4 h0 = hp[0], h1 = hp[1], h2 = hp[2], h3 = hp[3];
        float acc = h0.x*e0.x + h0.y*e0.y + h0.z*e0.z + h0.w*e0.w
                  + h1.x*e1.x + h1.y*e1.y + h1.z*e1.z + h1.w*e1.w
                  + h2.x*e2.x + h2.y*e2.y + h2.z*e2.z + h2.w*e2.w
                  + h3.x*e3.x + h3.y*e3.y + h3.z*e3.z + h3.w*e3.w;
        P.out[(long)(row0 + t) * Vc + tid] = acc;
      }
    }
  }
}

// ---------------------------------------------------------------------------
// launcher
// ---------------------------------------------------------------------------
extern "C" void kernel_launch(void* const* d_in, const int* in_sizes, int n_in,
                              void* d_out, int out_size, void* d_ws,
                              size_t ws_size, hipStream_t stream) {
  GPTParams P;
  P.idx  = (const int*)  d_in[0];
  P.tok  = (const float*)d_in[1];
  P.pos  = (const float*)d_in[2];
  P.wq   = (const float*)d_in[3];
  P.wk   = (const float*)d_in[4];
  P.wv   = (const float*)d_in[5];
  P.wo   = (const float*)d_in[6];
  P.ln1g = (const float*)d_in[7];
  P.ln1b = (const float*)d_in[8];
  P.ln2g = (const float*)d_in[9];
  P.ln2b = (const float*)d_in[10];
  P.w1   = (const float*)d_in[11];
  P.w2   = (const float*)d_in[12];
  P.lnfg = (const float*)d_in[13];
  P.lnfb = (const float*)d_in[14];
  P.out  = (float*)d_out;

  // workspace layout (floats):
  // x: 2MB | q,k,v: 2MB each | pacc: 32MB | pl: 4MB | barrier: 12B
  P.x    = (float*)d_ws;
  P.q    = P.x + (long)BT * Cc;
  P.k    = P.q + (long)Bc * Hc * Tc * HSc;
  P.v    = P.k + (long)Bc * Hc * Tc * HSc;
  P.pacc = P.v + (long)Bc * Hc * Tc * HSc;
  P.pl   = P.pacc + (long)Bc * Hc * NCH * Tc * HSc;
  P.bar  = (unsigned*)(P.pl + (long)Bc * Hc * NCH * Tc);

  microgpt_fused<<<NBLK, 256, 0, stream>>>(P);
}

// Round 8
// 301.088 us; speedup vs baseline: 2.0627x; 2.0627x over previous
//
#include <hip/hip_runtime.h>
#include <math.h>

// Problem constants (MicroGPT)
constexpr int Bc  = 16;
constexpr int Tc  = 2048;
constexpr int Cc  = 16;
constexpr int Hc  = 2;
constexpr int HSc = 8;
constexpr int Lc  = 2;
constexpr int Vc  = 256;
constexpr int BT  = Bc * Tc;          // 32768 tokens
constexpr float EPSc = 1e-5f;

// Attention v5: per-block full causal row of K-chunks, no partials.
constexpr int KC  = 128;              // keys per chunk (LDS tile)
constexpr int TQ  = 128;              // queries per block
constexpr int NQT = Tc / TQ;          // 16 query tiles

typedef float f2 __attribute__((ext_vector_type(2)));

__device__ inline float shx(float v, int m) { return __shfl_xor(v, m, 64); }

// ---------------------------------------------------------------------------
// LN helper
// ---------------------------------------------------------------------------
__device__ inline void layernorm16(const float* xr, float* h,
                                   const float* g, const float* b) {
  float m = 0.f;
#pragma unroll
  for (int c = 0; c < Cc; c++) m += xr[c];
  m *= (1.f / Cc);
  float var = 0.f;
#pragma unroll
  for (int c = 0; c < Cc; c++) { float d = xr[c] - m; var += d * d; }
  var *= (1.f / Cc);
  float rs = rsqrtf(var + EPSc);
#pragma unroll
  for (int c = 0; c < Cc; c++) h[c] = (xr[c] - m) * rs * g[c] + b[c];
}

// ---------------------------------------------------------------------------
// 4-lane-coop QKV: lane j computes s={2j,2j+1} of every (head, q/k/v) vector
// ---------------------------------------------------------------------------
__device__ inline void qkv_store_lane(const float* h, const float* swq,
                                      const float* swk, const float* swv,
                                      int bb, int tt, int j,
                                      float* __restrict__ q,
                                      float* __restrict__ k,
                                      float* __restrict__ v) {
#pragma unroll
  for (int hh = 0; hh < Hc; hh++) {
    float q0 = 0.f, q1 = 0.f, k0 = 0.f, k1 = 0.f, v0 = 0.f, v1 = 0.f;
#pragma unroll
    for (int c = 0; c < Cc; c++) {
      float hv = h[c];
      const float* wqp = swq + (hh * Cc + c) * HSc + 2 * j;
      const float* wkp = swk + (hh * Cc + c) * HSc + 2 * j;
      const float* wvp = swv + (hh * Cc + c) * HSc + 2 * j;
      q0 += hv * wqp[0]; q1 += hv * wqp[1];
      k0 += hv * wkp[0]; k1 += hv * wkp[1];
      v0 += hv * wvp[0]; v1 += hv * wvp[1];
    }
    long base = ((long)(bb * Hc + hh) * Tc + tt) * HSc;
    ((float2*)(q + base))[j] = make_float2(q0, q1);
    ((float2*)(k + base))[j] = make_float2(k0, k1);
    ((float2*)(v + base))[j] = make_float2(v0, v1);
  }
}

// ---------------------------------------------------------------------------
// K1) x = tok_emb[idx] + pos_emb ; h = LN1(x) ; q,k,v = h @ W  (layer 0)
// ---------------------------------------------------------------------------
__global__ __launch_bounds__(256) void embed_ln_qkv_kernel(
    const int* __restrict__ idx, const float* __restrict__ tok,
    const float* __restrict__ pos,
    const float* __restrict__ wq, const float* __restrict__ wk,
    const float* __restrict__ wv,
    const float* __restrict__ g, const float* __restrict__ b,
    float* __restrict__ x, float* __restrict__ q, float* __restrict__ k,
    float* __restrict__ v) {
  __shared__ float swq[256], swk[256], swv[256], sg[Cc], sb[Cc];
  int tid = threadIdx.x;
  swq[tid] = wq[tid];
  swk[tid] = wk[tid];
  swv[tid] = wv[tid];
  if (tid < Cc) { sg[tid] = g[tid]; sb[tid] = b[tid]; }
  __syncthreads();

  int tk = blockIdx.x * 64 + (tid >> 2);
  int j  = tid & 3;
  int tt = tk & (Tc - 1);
  int bb = tk >> 11;
  int id = idx[tk];
  float xr[Cc];
  const float4* te = (const float4*)(tok + id * Cc);
  const float4* pe = (const float4*)(pos + tt * Cc);
#pragma unroll
  for (int i = 0; i < 4; i++) {
    float4 a = te[i], p = pe[i];
    xr[4*i] = a.x + p.x; xr[4*i+1] = a.y + p.y;
    xr[4*i+2] = a.z + p.z; xr[4*i+3] = a.w + p.w;
  }
  ((float4*)(x + (long)tk * Cc))[j] =
      make_float4(xr[4*j], xr[4*j+1], xr[4*j+2], xr[4*j+3]);
  float h[Cc];
  layernorm16(xr, h, sg, sb);
  qkv_store_lane(h, swq, swk, swv, bb, tt, j, q, k, v);
}

// ---------------------------------------------------------------------------
// K2) Causal flash attention v5: block = (bh, qt) covers 128 queries over its
//     full causal K-range; 256 threads = 128 queries x 2 key-halves; K/V
//     chunks staged in LDS; halves combined via LDS; o written NORMALIZED.
//     No partials -> no pacc/pl traffic (was ~80 MB/layer round trip).
//     No max subtraction (|score| << 1 -> exp safe; softmax shift-invariant).
//     Block pairing blk<->blk+256 maps qt<->15-qt (balance heuristic only).
// ---------------------------------------------------------------------------
__global__ __launch_bounds__(256) void attn_kernel(
    const float* __restrict__ q, const float* __restrict__ k,
    const float* __restrict__ v, float* __restrict__ o) {
  int blk = blockIdx.x;                 // 0..511
  int bh  = blk & 31;
  int qt  = (blk < 256) ? (blk >> 5) : (NQT - 1 - ((blk - 256) >> 5));
  int tid = threadIdx.x;
  int ql  = tid & (TQ - 1);             // local query 0..127
  int half = tid >> 7;                  // key half 0/1 (wave-uniform)
  int qpos = qt * TQ + ql;

  __shared__ float sk[KC * HSc], sv[KC * HSc];   // 4 KB each
  __shared__ float sacc[TQ * HSc];               // 4 KB
  __shared__ float sl[TQ];

  const float pre = 0.35355339059327373f * 1.4426950408889634f;
  f2 qr[4], acc[4];
  {
    const f2* qp = (const f2*)(q + ((long)bh * Tc + qpos) * HSc);
#pragma unroll
    for (int jj = 0; jj < 4; jj++) {
      qr[jj] = qp[jj] * pre;
      acc[jj] = {0.f, 0.f};
    }
  }
  float l = 0.f;

  const float4* kb = (const float4*)(k + (long)bh * Tc * HSc);
  const float4* vb = (const float4*)(v + (long)bh * Tc * HSc);
  const f2* skp = (const f2*)sk + half * 64 * 4;   // this half's 64 rows
  const f2* svp = (const f2*)sv + half * 64 * 4;

  for (int ch = 0; ch <= qt; ch++) {
    __syncthreads();                    // prior iteration done reading LDS
    ((float4*)sk)[tid] = kb[ch * (KC * HSc / 4) + tid];
    ((float4*)sv)[tid] = vb[ch * (KC * HSc / 4) + tid];
    __syncthreads();
    if (ch < qt) {
#pragma unroll 4
      for (int u = 0; u < 64; u++) {
        f2 k0v = skp[u*4+0], k1v = skp[u*4+1],
           k2v = skp[u*4+2], k3v = skp[u*4+3];
        f2 d = qr[0] * k0v;
        d += qr[1] * k1v;
        d += qr[2] * k2v;
        d += qr[3] * k3v;
        float p = __builtin_amdgcn_exp2f(d.x + d.y);
        l += p;
        acc[0] += p * svp[u*4+0];
        acc[1] += p * svp[u*4+1];
        acc[2] += p * svp[u*4+2];
        acc[3] += p * svp[u*4+3];
      }
    } else {
      // diagonal chunk: key (half*64+u) valid iff <= ql  ->  u <= lim
      int lim = ql - half * 64;
      for (int u = 0; u < 64 && u <= lim; u++) {
        f2 k0v = skp[u*4+0], k1v = skp[u*4+1],
           k2v = skp[u*4+2], k3v = skp[u*4+3];
        f2 d = qr[0] * k0v;
        d += qr[1] * k1v;
        d += qr[2] * k2v;
        d += qr[3] * k3v;
        float p = __builtin_amdgcn_exp2f(d.x + d.y);
        l += p;
        acc[0] += p * svp[u*4+0];
        acc[1] += p * svp[u*4+1];
        acc[2] += p * svp[u*4+2];
        acc[3] += p * svp[u*4+3];
      }
    }
  }

  __syncthreads();                      // done with sk/sv reads
  if (half) {
    f2* sp = (f2*)(sacc + ql * HSc);
#pragma unroll
    for (int jj = 0; jj < 4; jj++) sp[jj] = acc[jj];
    sl[ql] = l;
  }
  __syncthreads();
  if (!half) {
    const f2* sp = (const f2*)(sacc + ql * HSc);
#pragma unroll
    for (int jj = 0; jj < 4; jj++) acc[jj] += sp[jj];
    l += sl[ql];
    float inv = 1.f / l;
    int bb = bh >> 1, hh = bh & 1;
    float* op = o + ((long)(bb * Tc + qpos)) * Cc + hh * HSc;
    ((float4*)op)[0] = make_float4(acc[0].x * inv, acc[0].y * inv,
                                   acc[1].x * inv, acc[1].y * inv);
    ((float4*)op)[1] = make_float4(acc[2].x * inv, acc[2].y * inv,
                                   acc[3].x * inv, acc[3].y * inv);
  }
}

// ---------------------------------------------------------------------------
// 4-lane cooperative tail: x += o@wo^T ; x += MLP(LN2(x))
// Lane roles (j = lane&3):
//   B: proj outputs c = 4j..4j+3    -> shfl_xor replicate
//   C: MLP hidden units j*16..+15   -> shfl_xor combine
// LDS: swo [16][17] padded, sw1 [64][17] padded, sw2 [16][64].
// ---------------------------------------------------------------------------
__device__ inline void coop_tail(
    const float* orow,
    const float* swo, const float* sw1, const float* sw2,
    const float* sg2, const float* sb2, int j, float* xr) {
  // --- B: proj, c = 4j..4j+3
  float xc[4];
#pragma unroll
  for (int qq = 0; qq < 4; qq++) {
    int c = 4 * j + qq;
    float acc = xr[c];
#pragma unroll
    for (int kk = 0; kk < Cc; kk++) acc += orow[kk] * swo[c * 17 + kk];
    xc[qq] = acc;
  }
  {
    float p[4];
#pragma unroll
    for (int qq = 0; qq < 4; qq++) p[qq] = shx(xc[qq], 1);
    bool lo = (j & 1) == 0;
    float a8[8], b8[8];
#pragma unroll
    for (int qq = 0; qq < 4; qq++) {
      a8[qq]     = lo ? xc[qq] : p[qq];
      a8[4 + qq] = lo ? p[qq] : xc[qq];
    }
#pragma unroll
    for (int s = 0; s < 8; s++) b8[s] = shx(a8[s], 2);
    bool lo2 = (j & 2) == 0;
#pragma unroll
    for (int s = 0; s < 8; s++) {
      xr[s]     = lo2 ? a8[s] : b8[s];
      xr[8 + s] = lo2 ? b8[s] : a8[s];
    }
  }
  // --- C: MLP, hidden units j*16..j*16+15
  float h[Cc];
  layernorm16(xr, h, sg2, sb2);
  float r[Cc];
#pragma unroll
  for (int c = 0; c < Cc; c++) r[c] = 0.f;
#pragma unroll
  for (int i = 0; i < 16; i++) {
    int jj = j * 16 + i;
    float acc = 0.f;
#pragma unroll
    for (int c = 0; c < Cc; c++) acc += h[c] * sw1[jj * 17 + c];
    acc = fmaxf(acc, 0.f);
#pragma unroll
    for (int c = 0; c < Cc; c++) r[c] += acc * sw2[c * 64 + jj];
  }
#pragma unroll
  for (int c = 0; c < Cc; c++) r[c] += shx(r[c], 1);
#pragma unroll
  for (int c = 0; c < Cc; c++) r[c] += shx(r[c], 2);
#pragma unroll
  for (int c = 0; c < Cc; c++) xr[c] += r[c];
}

// ---------------------------------------------------------------------------
// K3) layer-l epilogue + layer-(l+1) LN1+QKV  (4-lane coop, 512 blocks)
// ---------------------------------------------------------------------------
__global__ __launch_bounds__(256) void red_mid_kernel(
    const float* __restrict__ og,
    const float* __restrict__ wo, const float* __restrict__ g2,
    const float* __restrict__ b2, const float* __restrict__ w1,
    const float* __restrict__ w2,
    const float* __restrict__ wq, const float* __restrict__ wk,
    const float* __restrict__ wv, const float* __restrict__ g1,
    const float* __restrict__ b1,
    float* __restrict__ x, float* __restrict__ q, float* __restrict__ k,
    float* __restrict__ v) {
  __shared__ float swo[16 * 17], sw1[64 * 17], sw2[1024];
  __shared__ float swq[256], swk[256], swv[256];
  __shared__ float sg2[Cc], sb2[Cc], sg1[Cc], sb1[Cc];
  int tid = threadIdx.x;
  swq[tid] = wq[tid]; swk[tid] = wk[tid]; swv[tid] = wv[tid];
  { int rr = tid >> 4, c = tid & 15; swo[rr * 17 + c] = wo[tid]; }
#pragma unroll
  for (int t = tid; t < 1024; t += 256) {
    int jj = t >> 4, c = t & 15;
    sw1[jj * 17 + c] = w1[t];
    sw2[t] = w2[t];
  }
  if (tid < Cc) {
    sg2[tid] = g2[tid]; sb2[tid] = b2[tid];
    sg1[tid] = g1[tid]; sb1[tid] = b1[tid];
  }
  __syncthreads();

  int tk = blockIdx.x * 64 + (tid >> 2);
  int j  = tid & 3;
  int bb = tk >> 11, tt = tk & (Tc - 1);
  float xr[Cc], orow[Cc];
  const float4* xp = (const float4*)(x + (long)tk * Cc);
  const float4* op = (const float4*)(og + (long)tk * Cc);
#pragma unroll
  for (int i = 0; i < 4; i++) {
    float4 a = xp[i], b = op[i];
    xr[4*i]=a.x; xr[4*i+1]=a.y; xr[4*i+2]=a.z; xr[4*i+3]=a.w;
    orow[4*i]=b.x; orow[4*i+1]=b.y; orow[4*i+2]=b.z; orow[4*i+3]=b.w;
  }
  coop_tail(orow, swo, sw1, sw2, sg2, sb2, j, xr);
  ((float4*)(x + (long)tk * Cc))[j] =
      make_float4(xr[4*j], xr[4*j+1], xr[4*j+2], xr[4*j+3]);
  float h[Cc];
  layernorm16(xr, h, sg1, sb1);
  qkv_store_lane(h, swq, swk, swv, bb, tt, j, q, k, v);
}

// ---------------------------------------------------------------------------
// K5) final-layer epilogue + LNf + tied lm_head  (4-lane coop + head phase)
// ---------------------------------------------------------------------------
__global__ __launch_bounds__(256) void red_lnf_head_kernel(
    const float* __restrict__ og,
    const float* __restrict__ wo, const float* __restrict__ g2,
    const float* __restrict__ b2, const float* __restrict__ w1,
    const float* __restrict__ w2, const float* __restrict__ gf,
    const float* __restrict__ bf,
    const float* __restrict__ x, const float* __restrict__ tok,
    float* __restrict__ out) {
  __shared__ float swo[16 * 17], sw1[64 * 17], sw2[1024];
  __shared__ float sg2[Cc], sb2[Cc], sgf[Cc], sbf[Cc];
  __shared__ float sh[64 * Cc];
  int tid = threadIdx.x;
  { int rr = tid >> 4, c = tid & 15; swo[rr * 17 + c] = wo[tid]; }
#pragma unroll
  for (int t = tid; t < 1024; t += 256) {
    int jj = t >> 4, c = t & 15;
    sw1[jj * 17 + c] = w1[t];
    sw2[t] = w2[t];
  }
  if (tid < Cc) {
    sg2[tid] = g2[tid]; sb2[tid] = b2[tid];
    sgf[tid] = gf[tid]; sbf[tid] = bf[tid];
  }
  __syncthreads();

  int tk = blockIdx.x * 64 + (tid >> 2);
  int j  = tid & 3;
  float xr[Cc], orow[Cc];
  const float4* xp = (const float4*)(x + (long)tk * Cc);
  const float4* op = (const float4*)(og + (long)tk * Cc);
#pragma unroll
  for (int i = 0; i < 4; i++) {
    float4 a = xp[i], b = op[i];
    xr[4*i]=a.x; xr[4*i+1]=a.y; xr[4*i+2]=a.z; xr[4*i+3]=a.w;
    orow[4*i]=b.x; orow[4*i+1]=b.y; orow[4*i+2]=b.z; orow[4*i+3]=b.w;
  }
  coop_tail(orow, swo, sw1, sw2, sg2, sb2, j, xr);
  float h[Cc];
  layernorm16(xr, h, sgf, sbf);
  ((float4*)(sh + (tid >> 2) * Cc))[j] =
      make_float4(h[4*j], h[4*j+1], h[4*j+2], h[4*j+3]);
  __syncthreads();

  // head phase: thread = vocab id, 64 tokens from LDS (broadcast reads)
  float4 e0, e1, e2, e3;
  {
    const float4* ep = (const float4*)(tok + tid * Cc);
    e0 = ep[0]; e1 = ep[1]; e2 = ep[2]; e3 = ep[3];
  }
  int row0 = blockIdx.x * 64;
#pragma unroll 4
  for (int t = 0; t < 64; t++) {
    const float4* hp = (const float4*)(sh + t * Cc);
    float4 h0 = hp[0], h1 = hp[1], h2 = hp[2], h3 = hp[3];
    float acc = h0.x*e0.x + h0.y*e0.y + h0.z*e0.z + h0.w*e0.w
              + h1.x*e1.x + h1.y*e1.y + h1.z*e1.z + h1.w*e1.w
              + h2.x*e2.x + h2.y*e2.y + h2.z*e2.z + h2.w*e2.w
              + h3.x*e3.x + h3.y*e3.y + h3.z*e3.z + h3.w*e3.w;
    out[(long)(row0 + t) * Vc + tid] = acc;
  }
}

// ---------------------------------------------------------------------------
// launcher
// ---------------------------------------------------------------------------
extern "C" void kernel_launch(void* const* d_in, const int* in_sizes, int n_in,
                              void* d_out, int out_size, void* d_ws,
                              size_t ws_size, hipStream_t stream) {
  const int*   idx  = (const int*)  d_in[0];
  const float* tok  = (const float*)d_in[1];
  const float* pos  = (const float*)d_in[2];
  const float* wq   = (const float*)d_in[3];
  const float* wk   = (const float*)d_in[4];
  const float* wv   = (const float*)d_in[5];
  const float* wo   = (const float*)d_in[6];
  const float* ln1g = (const float*)d_in[7];
  const float* ln1b = (const float*)d_in[8];
  const float* ln2g = (const float*)d_in[9];
  const float* ln2b = (const float*)d_in[10];
  const float* w1   = (const float*)d_in[11];
  const float* w2   = (const float*)d_in[12];
  const float* lnfg = (const float*)d_in[13];
  const float* lnfb = (const float*)d_in[14];
  float* out = (float*)d_out;

  // workspace layout (floats): x, q, k, v, o  -> 5 x 2 MB = 10 MB
  float* x = (float*)d_ws;
  float* q = x + (long)BT * Cc;
  float* k = q + (long)Bc * Hc * Tc * HSc;
  float* v = k + (long)Bc * Hc * Tc * HSc;
  float* o = v + (long)Bc * Hc * Tc * HSc;

  embed_ln_qkv_kernel<<<BT / 64, 256, 0, stream>>>(
      idx, tok, pos, wq, wk, wv, ln1g, ln1b, x, q, k, v);
  attn_kernel<<<Bc * Hc * NQT, 256, 0, stream>>>(q, k, v, o);
  red_mid_kernel<<<BT / 64, 256, 0, stream>>>(
      o, wo, ln2g, ln2b, w1, w2,
      wq + Hc * Cc * HSc, wk + Hc * Cc * HSc, wv + Hc * Cc * HSc,
      ln1g + Cc, ln1b + Cc, x, q, k, v);
  attn_kernel<<<Bc * Hc * NQT, 256, 0, stream>>>(q, k, v, o);
  red_lnf_head_kernel<<<BT / 64, 256, 0, stream>>>(
      o, wo + Cc * Cc, ln2g + Cc, ln2b + Cc,
      w1 + 4 * Cc * Cc, w2 + 4 * Cc * Cc, lnfg, lnfb, x, tok, out);
}

// Round 9
// 229.038 us; speedup vs baseline: 2.7115x; 1.3146x over previous
//
#include <hip/hip_runtime.h>
#include <math.h>

// Problem constants (MicroGPT)
constexpr int Bc  = 16;
constexpr int Tc  = 2048;
constexpr int Cc  = 16;
constexpr int Hc  = 2;
constexpr int HSc = 8;
constexpr int Lc  = 2;
constexpr int Vc  = 256;
constexpr int BT  = Bc * Tc;          // 32768 tokens
constexpr float EPSc = 1e-5f;

// Attention tiling: K-chunk split + 4 CONSECUTIVE queries/thread
constexpr int KC  = 128;              // keys per chunk (LDS tile)
constexpr int NCH = Tc / KC;          // 16 chunks
constexpr int QB  = 1024;             // queries per block (256 thr x 4)
constexpr int NQB = Tc / QB;          // 2 query blocks per (b,h)

typedef float f2 __attribute__((ext_vector_type(2)));

__device__ inline float shx(float v, int m) { return __shfl_xor(v, m, 64); }

// ---------------------------------------------------------------------------
// LN helper
// ---------------------------------------------------------------------------
__device__ inline void layernorm16(const float* xr, float* h,
                                   const float* g, const float* b) {
  float m = 0.f;
#pragma unroll
  for (int c = 0; c < Cc; c++) m += xr[c];
  m *= (1.f / Cc);
  float var = 0.f;
#pragma unroll
  for (int c = 0; c < Cc; c++) { float d = xr[c] - m; var += d * d; }
  var *= (1.f / Cc);
  float rs = rsqrtf(var + EPSc);
#pragma unroll
  for (int c = 0; c < Cc; c++) h[c] = (xr[c] - m) * rs * g[c] + b[c];
}

// ---------------------------------------------------------------------------
// 4-lane-coop QKV: lane j computes s={2j,2j+1} of every (head, q/k/v) vector
// ---------------------------------------------------------------------------
__device__ inline void qkv_store_lane(const float* h, const float* swq,
                                      const float* swk, const float* swv,
                                      int bb, int tt, int j,
                                      float* __restrict__ q,
                                      float* __restrict__ k,
                                      float* __restrict__ v) {
#pragma unroll
  for (int hh = 0; hh < Hc; hh++) {
    float q0 = 0.f, q1 = 0.f, k0 = 0.f, k1 = 0.f, v0 = 0.f, v1 = 0.f;
#pragma unroll
    for (int c = 0; c < Cc; c++) {
      float hv = h[c];
      const float* wqp = swq + (hh * Cc + c) * HSc + 2 * j;
      const float* wkp = swk + (hh * Cc + c) * HSc + 2 * j;
      const float* wvp = swv + (hh * Cc + c) * HSc + 2 * j;
      q0 += hv * wqp[0]; q1 += hv * wqp[1];
      k0 += hv * wkp[0]; k1 += hv * wkp[1];
      v0 += hv * wvp[0]; v1 += hv * wvp[1];
    }
    long base = ((long)(bb * Hc + hh) * Tc + tt) * HSc;
    ((float2*)(q + base))[j] = make_float2(q0, q1);
    ((float2*)(k + base))[j] = make_float2(k0, k1);
    ((float2*)(v + base))[j] = make_float2(v0, v1);
  }
}

// ---------------------------------------------------------------------------
// K1) x = tok_emb[idx] + pos_emb ; h = LN1(x) ; q,k,v = h @ W  (layer 0)
// ---------------------------------------------------------------------------
__global__ __launch_bounds__(256, 4) void embed_ln_qkv_kernel(
    const int* __restrict__ idx, const float* __restrict__ tok,
    const float* __restrict__ pos,
    const float* __restrict__ wq, const float* __restrict__ wk,
    const float* __restrict__ wv,
    const float* __restrict__ g, const float* __restrict__ b,
    float* __restrict__ x, float* __restrict__ q, float* __restrict__ k,
    float* __restrict__ v) {
  __shared__ float swq[256], swk[256], swv[256], sg[Cc], sb[Cc];
  int tid = threadIdx.x;
  swq[tid] = wq[tid];
  swk[tid] = wk[tid];
  swv[tid] = wv[tid];
  if (tid < Cc) { sg[tid] = g[tid]; sb[tid] = b[tid]; }
  __syncthreads();

  int tk = blockIdx.x * 64 + (tid >> 2);
  int j  = tid & 3;
  int tt = tk & (Tc - 1);
  int bb = tk >> 11;
  int id = idx[tk];
  float xr[Cc];
  const float4* te = (const float4*)(tok + id * Cc);
  const float4* pe = (const float4*)(pos + tt * Cc);
#pragma unroll
  for (int i = 0; i < 4; i++) {
    float4 a = te[i], p = pe[i];
    xr[4*i] = a.x + p.x; xr[4*i+1] = a.y + p.y;
    xr[4*i+2] = a.z + p.z; xr[4*i+3] = a.w + p.w;
  }
  ((float4*)(x + (long)tk * Cc))[j] =
      make_float4(xr[4*j], xr[4*j+1], xr[4*j+2], xr[4*j+3]);
  float h[Cc];
  layernorm16(xr, h, sg, sb);
  qkv_store_lane(h, swq, swk, swv, bb, tt, j, q, k, v);
}

// ---------------------------------------------------------------------------
// K2) Causal flash attention, K-chunk split, 4 CONSECUTIVE queries/thread.
//     Thread's queries = q0..q0+3 -> causal boundary is a <=3-step epilogue;
//     hot loop is unmasked (was 38% masked waste with strided queries).
//     Writes UNNORMALIZED partials (acc[8], l) per (query, chunk).
//     No max subtraction (|score| << 1 -> exp safe; softmax shift-invariant).
// ---------------------------------------------------------------------------
__global__ __launch_bounds__(256, 4) void attn_kernel(
    const float* __restrict__ q, const float* __restrict__ k,
    const float* __restrict__ v, float* __restrict__ pacc,
    float* __restrict__ pl) {
  int bh = blockIdx.x;            // 0..31
  int ch = blockIdx.y;            // 0..15
  int qb = blockIdx.z;            // 0..1
  int k0 = ch * KC;
  if (k0 >= (qb + 1) * QB) return;       // chunk entirely in causal future

  __shared__ float sk[KC * HSc], sv[KC * HSc];
  int tid = threadIdx.x;
  {
    const float4* ksrc = (const float4*)(k + ((long)bh * Tc + k0) * HSc);
    const float4* vsrc = (const float4*)(v + ((long)bh * Tc + k0) * HSc);
    ((float4*)sk)[tid] = ksrc[tid];      // KC*HSc/4 == 256 == blockDim
    ((float4*)sv)[tid] = vsrc[tid];
  }
  __syncthreads();

  const float pre = 0.35355339059327373f * 1.4426950408889634f;
  int q0 = qb * QB + 4 * tid;     // 4 consecutive queries q0..q0+3
  int t1 = q0 - k0;               // key u is unmasked for ALL queries iff u<=t1
  f2 qr[4][4];
  f2 acc[4][4];
  float l4[4] = {0.f, 0.f, 0.f, 0.f};
  {
    // 4 consecutive q rows = 32 contiguous floats
    const f2* qp = (const f2*)(q + ((long)bh * Tc + q0) * HSc);
#pragma unroll
    for (int i = 0; i < 4; i++)
#pragma unroll
      for (int jj = 0; jj < 4; jj++) {
        qr[i][jj] = qp[i * 4 + jj] * pre;
        acc[i][jj] = {0.f, 0.f};
      }
  }

  const f2* skp = (const f2*)sk;
  const f2* svp = (const f2*)sv;

#define ATTN_STEP(u, MASKED)                                              \
  {                                                                       \
    f2 k0v = skp[(u)*4+0], k1v = skp[(u)*4+1],                            \
       k2v = skp[(u)*4+2], k3v = skp[(u)*4+3];                            \
    f2 v0v = svp[(u)*4+0], v1v = svp[(u)*4+1],                            \
       v2v = svp[(u)*4+2], v3v = svp[(u)*4+3];                            \
    _Pragma("unroll")                                                     \
    for (int i = 0; i < 4; i++) {                                         \
      f2 d = qr[i][0] * k0v;                                              \
      d += qr[i][1] * k1v;                                                \
      d += qr[i][2] * k2v;                                                \
      d += qr[i][3] * k3v;                                                \
      float s = d.x + d.y;                                                \
      float p = __builtin_amdgcn_exp2f(s);                                \
      if (MASKED) p = ((u) - t1 <= i) ? p : 0.f;                          \
      l4[i] += p;                                                         \
      acc[i][0] += p * v0v;                                               \
      acc[i][1] += p * v1v;                                               \
      acc[i][2] += p * v2v;                                               \
      acc[i][3] += p * v3v;                                               \
    }                                                                     \
  }

  bool full = (k0 + KC) <= qb * QB;   // block-uniform: all queries see all keys
  if (full) {
#pragma unroll 2
    for (int u = 0; u < KC; u++) ATTN_STEP(u, false)
  } else {
    int nfull = t1 + 1;                       // u < nfull: all 4 unmasked
    if (nfull > KC) nfull = KC;
    int nend = t1 + 4;                        // u < nend: some query valid
    if (nend < 0) nend = 0;
    if (nend > KC) nend = KC;
#pragma unroll 2
    for (int u = 0; u < nfull; u++) ATTN_STEP(u, false)
    for (int u = (nfull > 0 ? nfull : 0); u < nend; u++) ATTN_STEP(u, true)
  }
#undef ATTN_STEP

  long rec = (long)(bh * NCH + ch) * Tc + q0;
#pragma unroll
  for (int i = 0; i < 4; i++) {
    if (t1 + i + 1 > 0) {
      float4* pa = (float4*)(pacc + (rec + i) * 8);
      pa[0] = make_float4(acc[i][0].x, acc[i][0].y, acc[i][1].x, acc[i][1].y);
      pa[1] = make_float4(acc[i][2].x, acc[i][2].y, acc[i][3].x, acc[i][3].y);
      pl[rec + i] = l4[i];
    }
  }
}

// ---------------------------------------------------------------------------
// 4-lane cooperative tail: reduce partials -> o ; x += o@wo^T ; x += MLP(LN2)
// Lane roles (j = lane&3):
//   A: head j&1, chunks (j>>1)::2   -> shfl_xor combine
//   B: proj outputs c = 4j..4j+3    -> shfl_xor replicate
//   C: MLP hidden units j*16..+15   -> shfl_xor combine
// LDS layouts: swo [16][17] padded, sw1 [64][17] padded, sw2 [16][64].
// ---------------------------------------------------------------------------
__device__ inline void coop_tail(
    const float* __restrict__ pacc, const float* __restrict__ pl,
    const float* swo, const float* sw1, const float* sw2,
    const float* sg2, const float* sb2, int bb, int tt, int j, float* xr) {
  // --- A: attention partial reduce
  int hh  = j & 1;
  int bh  = bb * Hc + hh;
  int nch = tt / KC + 1;
  float o8[8] = {0,0,0,0,0,0,0,0};
  float l = 0.f;
#pragma unroll 2
  for (int ch = (j >> 1); ch < nch; ch += 2) {
    long rec = (long)(bh * NCH + ch) * Tc + tt;
    const float4* pa = (const float4*)(pacc + rec * 8);
    float4 a = pa[0], b = pa[1];
    o8[0]+=a.x; o8[1]+=a.y; o8[2]+=a.z; o8[3]+=a.w;
    o8[4]+=b.x; o8[5]+=b.y; o8[6]+=b.z; o8[7]+=b.w;
    l += pl[rec];
  }
#pragma unroll
  for (int s = 0; s < 8; s++) o8[s] += shx(o8[s], 2);
  l += shx(l, 2);
  float inv = 1.f / l;
  float own[8], oth[8];
#pragma unroll
  for (int s = 0; s < 8; s++) own[s] = o8[s] * inv;
#pragma unroll
  for (int s = 0; s < 8; s++) oth[s] = shx(own[s], 1);
  float orow[Cc];
#pragma unroll
  for (int s = 0; s < 8; s++) {
    orow[s]     = (hh == 0) ? own[s] : oth[s];
    orow[8 + s] = (hh == 0) ? oth[s] : own[s];
  }
  // --- B: proj, c = 4j..4j+3
  float xc[4];
#pragma unroll
  for (int qq = 0; qq < 4; qq++) {
    int c = 4 * j + qq;
    float acc = xr[c];
#pragma unroll
    for (int kk = 0; kk < Cc; kk++) acc += orow[kk] * swo[c * 17 + kk];
    xc[qq] = acc;
  }
  {
    float p[4];
#pragma unroll
    for (int qq = 0; qq < 4; qq++) p[qq] = shx(xc[qq], 1);
    bool lo = (j & 1) == 0;
    float a8[8], b8[8];
#pragma unroll
    for (int qq = 0; qq < 4; qq++) {
      a8[qq]     = lo ? xc[qq] : p[qq];
      a8[4 + qq] = lo ? p[qq] : xc[qq];
    }
#pragma unroll
    for (int s = 0; s < 8; s++) b8[s] = shx(a8[s], 2);
    bool lo2 = (j & 2) == 0;
#pragma unroll
    for (int s = 0; s < 8; s++) {
      xr[s]     = lo2 ? a8[s] : b8[s];
      xr[8 + s] = lo2 ? b8[s] : a8[s];
    }
  }
  // --- C: MLP, hidden units j*16..j*16+15
  float h[Cc];
  layernorm16(xr, h, sg2, sb2);
  float r[Cc];
#pragma unroll
  for (int c = 0; c < Cc; c++) r[c] = 0.f;
#pragma unroll
  for (int i = 0; i < 16; i++) {
    int jj = j * 16 + i;
    float acc = 0.f;
#pragma unroll
    for (int c = 0; c < Cc; c++) acc += h[c] * sw1[jj * 17 + c];
    acc = fmaxf(acc, 0.f);
#pragma unroll
    for (int c = 0; c < Cc; c++) r[c] += acc * sw2[c * 64 + jj];
  }
#pragma unroll
  for (int c = 0; c < Cc; c++) r[c] += shx(r[c], 1);
#pragma unroll
  for (int c = 0; c < Cc; c++) r[c] += shx(r[c], 2);
#pragma unroll
  for (int c = 0; c < Cc; c++) xr[c] += r[c];
}

// ---------------------------------------------------------------------------
// K3) layer-l epilogue + layer-(l+1) LN1+QKV  (4-lane coop, 512 blocks)
// ---------------------------------------------------------------------------
__global__ __launch_bounds__(256, 4) void red_mid_kernel(
    const float* __restrict__ pacc, const float* __restrict__ pl,
    const float* __restrict__ wo, const float* __restrict__ g2,
    const float* __restrict__ b2, const float* __restrict__ w1,
    const float* __restrict__ w2,
    const float* __restrict__ wq, const float* __restrict__ wk,
    const float* __restrict__ wv, const float* __restrict__ g1,
    const float* __restrict__ b1,
    float* __restrict__ x, float* __restrict__ q, float* __restrict__ k,
    float* __restrict__ v) {
  __shared__ float swo[16 * 17], sw1[64 * 17], sw2[1024];
  __shared__ float swq[256], swk[256], swv[256];
  __shared__ float sg2[Cc], sb2[Cc], sg1[Cc], sb1[Cc];
  int tid = threadIdx.x;
  swq[tid] = wq[tid]; swk[tid] = wk[tid]; swv[tid] = wv[tid];
  { int rr = tid >> 4, c = tid & 15; swo[rr * 17 + c] = wo[tid]; }
#pragma unroll
  for (int t = tid; t < 1024; t += 256) {
    int jj = t >> 4, c = t & 15;
    sw1[jj * 17 + c] = w1[t];
    sw2[t] = w2[t];
  }
  if (tid < Cc) {
    sg2[tid] = g2[tid]; sb2[tid] = b2[tid];
    sg1[tid] = g1[tid]; sb1[tid] = b1[tid];
  }
  __syncthreads();

  int tk = blockIdx.x * 64 + (tid >> 2);
  int j  = tid & 3;
  int bb = tk >> 11, tt = tk & (Tc - 1);
  float xr[Cc];
  const float4* xp = (const float4*)(x + (long)tk * Cc);
#pragma unroll
  for (int i = 0; i < 4; i++) {
    float4 a = xp[i];
    xr[4*i]=a.x; xr[4*i+1]=a.y; xr[4*i+2]=a.z; xr[4*i+3]=a.w;
  }
  coop_tail(pacc, pl, swo, sw1, sw2, sg2, sb2, bb, tt, j, xr);
  ((float4*)(x + (long)tk * Cc))[j] =
      make_float4(xr[4*j], xr[4*j+1], xr[4*j+2], xr[4*j+3]);
  float h[Cc];
  layernorm16(xr, h, sg1, sb1);
  qkv_store_lane(h, swq, swk, swv, bb, tt, j, q, k, v);
}

// ---------------------------------------------------------------------------
// K5) final-layer epilogue + LNf + tied lm_head  (4-lane coop + head phase)
// ---------------------------------------------------------------------------
__global__ __launch_bounds__(256, 4) void red_lnf_head_kernel(
    const float* __restrict__ pacc, const float* __restrict__ pl,
    const float* __restrict__ wo, const float* __restrict__ g2,
    const float* __restrict__ b2, const float* __restrict__ w1,
    const float* __restrict__ w2, const float* __restrict__ gf,
    const float* __restrict__ bf,
    const float* __restrict__ x, const float* __restrict__ tok,
    float* __restrict__ out) {
  __shared__ float swo[16 * 17], sw1[64 * 17], sw2[1024];
  __shared__ float sg2[Cc], sb2[Cc], sgf[Cc], sbf[Cc];
  __shared__ float sh[64 * Cc];
  int tid = threadIdx.x;
  { int rr = tid >> 4, c = tid & 15; swo[rr * 17 + c] = wo[tid]; }
#pragma unroll
  for (int t = tid; t < 1024; t += 256) {
    int jj = t >> 4, c = t & 15;
    sw1[jj * 17 + c] = w1[t];
    sw2[t] = w2[t];
  }
  if (tid < Cc) {
    sg2[tid] = g2[tid]; sb2[tid] = b2[tid];
    sgf[tid] = gf[tid]; sbf[tid] = bf[tid];
  }
  __syncthreads();

  int tk = blockIdx.x * 64 + (tid >> 2);
  int j  = tid & 3;
  int bb = tk >> 11, tt = tk & (Tc - 1);
  float xr[Cc];
  const float4* xp = (const float4*)(x + (long)tk * Cc);
#pragma unroll
  for (int i = 0; i < 4; i++) {
    float4 a = xp[i];
    xr[4*i]=a.x; xr[4*i+1]=a.y; xr[4*i+2]=a.z; xr[4*i+3]=a.w;
  }
  coop_tail(pacc, pl, swo, sw1, sw2, sg2, sb2, bb, tt, j, xr);
  float h[Cc];
  layernorm16(xr, h, sgf, sbf);
  ((float4*)(sh + (tid >> 2) * Cc))[j] =
      make_float4(h[4*j], h[4*j+1], h[4*j+2], h[4*j+3]);
  __syncthreads();

  // head phase: thread = vocab id, 64 tokens from LDS (broadcast reads)
  float4 e0, e1, e2, e3;
  {
    const float4* ep = (const float4*)(tok + tid * Cc);
    e0 = ep[0]; e1 = ep[1]; e2 = ep[2]; e3 = ep[3];
  }
  int row0 = blockIdx.x * 64;
#pragma unroll 4
  for (int t = 0; t < 64; t++) {
    const float4* hp = (const float4*)(sh + t * Cc);
    float4 h0 = hp[0], h1 = hp[1], h2 = hp[2], h3 = hp[3];
    float acc = h0.x*e0.x + h0.y*e0.y + h0.z*e0.z + h0.w*e0.w
              + h1.x*e1.x + h1.y*e1.y + h1.z*e1.z + h1.w*e1.w
              + h2.x*e2.x + h2.y*e2.y + h2.z*e2.z + h2.w*e2.w
              + h3.x*e3.x + h3.y*e3.y + h3.z*e3.z + h3.w*e3.w;
    out[(long)(row0 + t) * Vc + tid] = acc;
  }
}

// ---------------------------------------------------------------------------
// launcher
// ---------------------------------------------------------------------------
extern "C" void kernel_launch(void* const* d_in, const int* in_sizes, int n_in,
                              void* d_out, int out_size, void* d_ws,
                              size_t ws_size, hipStream_t stream) {
  const int*   idx  = (const int*)  d_in[0];
  const float* tok  = (const float*)d_in[1];
  const float* pos  = (const float*)d_in[2];
  const float* wq   = (const float*)d_in[3];
  const float* wk   = (const float*)d_in[4];
  const float* wv   = (const float*)d_in[5];
  const float* wo   = (const float*)d_in[6];
  const float* ln1g = (const float*)d_in[7];
  const float* ln1b = (const float*)d_in[8];
  const float* ln2g = (const float*)d_in[9];
  const float* ln2b = (const float*)d_in[10];
  const float* w1   = (const float*)d_in[11];
  const float* w2   = (const float*)d_in[12];
  const float* lnfg = (const float*)d_in[13];
  const float* lnfb = (const float*)d_in[14];
  float* out = (float*)d_out;

  // workspace layout (floats):
  // x: 2MB | q,k,v: 2MB each | pacc: 32MB | pl: 4MB
  float* x    = (float*)d_ws;
  float* q    = x + (long)BT * Cc;
  float* k    = q + (long)Bc * Hc * Tc * HSc;
  float* v    = k + (long)Bc * Hc * Tc * HSc;
  float* pacc = v + (long)Bc * Hc * Tc * HSc;
  float* pl   = pacc + (long)Bc * Hc * NCH * Tc * HSc;

  dim3 agrid(Bc * Hc, NCH, NQB);

  embed_ln_qkv_kernel<<<BT / 64, 256, 0, stream>>>(
      idx, tok, pos, wq, wk, wv, ln1g, ln1b, x, q, k, v);
  attn_kernel<<<agrid, 256, 0, stream>>>(q, k, v, pacc, pl);
  red_mid_kernel<<<BT / 64, 256, 0, stream>>>(
      pacc, pl, wo, ln2g, ln2b, w1, w2,
      wq + Hc * Cc * HSc, wk + Hc * Cc * HSc, wv + Hc * Cc * HSc,
      ln1g + Cc, ln1b + Cc, x, q, k, v);
  attn_kernel<<<agrid, 256, 0, stream>>>(q, k, v, pacc, pl);
  red_lnf_head_kernel<<<BT / 64, 256, 0, stream>>>(
      pacc, pl, wo + Cc * Cc, ln2g + Cc, ln2b + Cc,
      w1 + 4 * Cc * Cc, w2 + 4 * Cc * Cc, lnfg, lnfb, x, tok, out);
}